// Round 8
// baseline (56.155 us; speedup 1.0000x reference)
//
#include <hip/hip_runtime.h>
#include <cstddef>

#define NUM_BLOCKS 8
#define BLK 512
#define D_IN 2048
#define NROWS 8192
#define NBUCKETS (NUM_BLOCKS * BLK) /* 4096 */
#define CAP 32                      /* int-ELL padded capacity (tail path) */
#define ROWS_PER_WG 8
#define THREADS 512
#define SENT 4096                   /* sentinel entry -> zeroed LDS row 2048 */

typedef float    v4f __attribute__((ext_vector_type(4)));
typedef unsigned v4u __attribute__((ext_vector_type(4)));

// Build inverted index: one WAVE per bucket. Ballot-match, ascending-d
// placement via popcount prefix. Outputs:
//  - entries16[bucket][8]: packed ushort ELL (first 8 entries, sentinel=4096)
//  - entries[bucket][CAP]: int ELL (sentinel-padded to chunk of 4) for tails
//  - nchunks[bucket]: total int4 chunks (tail runs chunks 2..nch)
__global__ __launch_bounds__(256) void cs_build_index(
    const int* __restrict__ i_hash, const float* __restrict__ s_hash,
    int* __restrict__ nchunks, int* __restrict__ entries,
    unsigned short* __restrict__ entries16)
{
    const int gid  = blockIdx.x * blockDim.x + threadIdx.x;
    const int wave = gid >> 6;            // bucket id
    const int lane = threadIdx.x & 63;
    if (wave >= NBUCKETS) return;
    const int b = wave >> 9;
    const int k = wave & (BLK - 1);
    const int*   ih = i_hash + b * D_IN;
    const float* sr = s_hash + b * D_IN;
    int* erow = entries + wave * CAP;
    unsigned short* e16 = entries16 + wave * 8;
    int cnt = 0;
    for (int d0 = 0; d0 < D_IN; d0 += 64) {
        const int d = d0 + lane;
        const bool m = (ih[d] == k);
        const unsigned long long mask = __ballot(m);
        if (m) {
            const int pos = cnt + __popcll(mask & ((1ull << lane) - 1ull));
            const int ent = (d << 1) | ((sr[d] < 0.0f) ? 1 : 0);
            if (pos < CAP) erow[pos] = ent;
            if (pos < 8)   e16[pos]  = (unsigned short)ent;
        }
        cnt += (int)__popcll(mask);
    }
    if (cnt > CAP) cnt = CAP;
    int nch = (cnt + 3) >> 2;
    if (nch == 0) nch = 1;
    if (lane >= cnt) {
        if (lane < 8)       e16[lane]  = (unsigned short)SENT;
        if (lane < nch * 4) erow[lane] = SENT;
    }
    if (lane == 0) nchunks[wave] = nch;
}

// Gather: 8 rows/WG staged as RNE-rounded bf16, transposed: xs4[d] is one
// 16B word holding all 8 rows -> ONE ds_read_b128 per entry serves 8 rows.
// Sign applied via XOR 0x80008000 on packed pairs; sentinel row 2048 is
// zeros (+0.0 adds). Thread t handles 4 consecutive buckets x 2 groups so
// outputs leave as coalesced float4 NT stores. Fixed 8-entry branch-free
// unroll; rare cnt>8 tail from int-ELL (L2). No register-held staging
// across compute; single barrier.
__global__ __launch_bounds__(THREADS, 4) void cs_gather(
    const float* __restrict__ x, const int* __restrict__ nchunks,
    const int* __restrict__ entries, const v4u* __restrict__ entries16,
    float* __restrict__ out)
{
    __shared__ v4u xs4[D_IN + 1];   // 32784 B; row d = 8 bf16 (rows 0..7)
    const int tid  = threadIdx.x;
    const int row0 = blockIdx.x * ROWS_PER_WG;

    // Descriptor loads first (independent of LDS; latency hides in staging).
    v4u e8[8];
    int nch[8];
#pragma unroll
    for (int g = 0; g < 2; ++g)
#pragma unroll
        for (int q = 0; q < 4; ++q) {
            const int j = 4 * (tid + 512 * g) + q;
            e8[g * 4 + q]  = entries16[j];
            nch[g * 4 + q] = nchunks[j];
        }

    if (tid == 0) xs4[D_IN] = (v4u){0u, 0u, 0u, 0u};  // sentinel row

    // Stage transposed bf16: thread owns d in {tid, tid+512, ...}; 8
    // coalesced dword loads -> RNE-round -> pack pairs -> 1 ds_write_b128.
    const size_t b0 = (size_t)row0 * D_IN;
#pragma unroll
    for (int i = 0; i < 4; ++i) {
        const int d = tid + i * THREADS;
        unsigned r[8];
#pragma unroll
        for (int rr = 0; rr < 8; ++rr) {
            const unsigned u = __float_as_uint(x[b0 + (size_t)rr * D_IN + d]);
            r[rr] = (u + 0x7fffu + ((u >> 16) & 1u)) >> 16;  // RNE bf16
        }
        v4u w;
        w.x = r[0] | (r[1] << 16);
        w.y = r[2] | (r[3] << 16);
        w.z = r[4] | (r[5] << 16);
        w.w = r[6] | (r[7] << 16);
        xs4[d] = w;
    }
    __syncthreads();

    const float scale = 0.35355339059327373f; // 1/sqrt(8)
#define ASF __uint_as_float

    // One b128 read + sign-xor + unpack-add for 8 rows. A = float[8].
#define PE(e, A)                                                          \
    do {                                                                  \
        const unsigned ue = (unsigned)(e);                                \
        const unsigned sm = (ue & 1u) ? 0x80008000u : 0u;                 \
        const v4u w = xs4[ue >> 1];                                       \
        const unsigned w0 = w.x ^ sm, w1 = w.y ^ sm;                      \
        const unsigned w2 = w.z ^ sm, w3 = w.w ^ sm;                      \
        A[0] += ASF(w0 << 16); A[1] += ASF(w0 & 0xffff0000u);             \
        A[2] += ASF(w1 << 16); A[3] += ASF(w1 & 0xffff0000u);             \
        A[4] += ASF(w2 << 16); A[5] += ASF(w2 & 0xffff0000u);             \
        A[6] += ASF(w3 << 16); A[7] += ASF(w3 & 0xffff0000u);             \
    } while (0)

#pragma unroll
    for (int g = 0; g < 2; ++g) {
        const int col4 = tid + 512 * g;       // float4-column index
        float acc[4][8];
#pragma unroll
        for (int q = 0; q < 4; ++q)
#pragma unroll
            for (int rr = 0; rr < 8; ++rr) acc[q][rr] = 0.0f;

#pragma unroll
        for (int q = 0; q < 4; ++q) {
            const v4u ew = e8[g * 4 + q];
            PE(ew.x & 0xffffu, acc[q]); PE(ew.x >> 16, acc[q]);
            PE(ew.y & 0xffffu, acc[q]); PE(ew.y >> 16, acc[q]);
            PE(ew.z & 0xffffu, acc[q]); PE(ew.z >> 16, acc[q]);
            PE(ew.w & 0xffffu, acc[q]);
            PE(ew.w >> 16, acc[q]);
            const int n = nch[g * 4 + q];
            if (n > 2) {                      // rare (~2% of buckets)
                const int j = 4 * col4 + q;
                const int4* __restrict__ ep = (const int4*)(entries + j * CAP);
#pragma unroll 1
                for (int c = 2; c < n; ++c) {
                    const int4 cc = ep[c];
                    PE(cc.x, acc[q]); PE(cc.y, acc[q]);
                    PE(cc.z, acc[q]); PE(cc.w, acc[q]);
                }
            }
        }
        // 8 rows x one float4 NT store each (coalesced 16B/lane).
#pragma unroll
        for (int rr = 0; rr < 8; ++rr) {
            v4f v = { acc[0][rr] * scale, acc[1][rr] * scale,
                      acc[2][rr] * scale, acc[3][rr] * scale };
            __builtin_nontemporal_store(
                v, (v4f*)(out + (size_t)(row0 + rr) * NBUCKETS + 4 * col4));
        }
    }
#undef PE
#undef ASF
}

extern "C" void kernel_launch(void* const* d_in, const int* in_sizes, int n_in,
                              void* d_out, int out_size, void* d_ws, size_t ws_size,
                              hipStream_t stream)
{
    const float* x      = (const float*)d_in[0];
    const float* s_hash = (const float*)d_in[1];
    const int*   i_hash = (const int*)d_in[2];
    float* out = (float*)d_out;

    // ws: nchunks[4096] (16KB) | entries[4096][32] (512KB) | entries16 (64KB)
    int* nchunks = (int*)d_ws;
    int* entries = nchunks + NBUCKETS;
    unsigned short* entries16 = (unsigned short*)(entries + NBUCKETS * CAP);

    cs_build_index<<<(NBUCKETS * 64) / 256, 256, 0, stream>>>(
        i_hash, s_hash, nchunks, entries, entries16);
    cs_gather<<<NROWS / ROWS_PER_WG, THREADS, 0, stream>>>(
        x, nchunks, entries, (const v4u*)entries16, out);
}